// Round 4
// baseline (458.688 us; speedup 1.0000x reference)
//
#include <hip/hip_runtime.h>
#include <hip/hip_cooperative_groups.h>

namespace cg = cooperative_groups;

typedef unsigned int uint32;

__device__ __forceinline__ float fexp2(float x) { return __builtin_amdgcn_exp2f(x); }
__device__ __forceinline__ float flog2(float x) { return __builtin_amdgcn_logf(x); }

__device__ __forceinline__ float s2lin(float c) {
    float p = fexp2(flog2((c + 0.055f) * (1.0f / 1.055f)) * 2.4f);
    return c > 0.04045f ? p : c * (1.0f / 12.92f);
}

__device__ __forceinline__ float labf(float t) {
    float p = fexp2(flog2(t) * (1.0f / 3.0f));
    return t > 0.008856f ? p : 7.787f * t + (16.0f / 116.0f);
}

__device__ __forceinline__ void px(float r, float g, float b,
                                   float& L, float& a01, float& b01) {
    float lr = s2lin(r), lg = s2lin(g), lb = s2lin(b);
    // RGB2XYZ rows pre-divided by D65 white (0.95047, 1.0, 1.08883)
    float X = 0.43395300f * lr + 0.37621900f * lg + 0.18982460f * lb;
    float Y = 0.21267100f * lr + 0.71516000f * lg + 0.07216900f * lb;
    float Z = 0.01775660f * lr + 0.10946970f * lg + 0.87270740f * lb;
    float fx = labf(X), fy = labf(Y), fz = labf(Z);
    L   = 116.0f * fy - 16.0f;                              // L in [0,100]
    a01 = (500.0f * (fx - fy) + 128.0f) * (1.0f / 255.0f);
    b01 = (200.0f * (fy - fz) + 128.0f) * (1.0f / 255.0f);
}

__device__ __forceinline__ uint32 packpx(float L, float a01, float b01) {
    uint32 au = (uint32)(a01 * 255.0f + 0.5f);
    uint32 bu = (uint32)(b01 * 255.0f + 0.5f);
    unsigned short hb = __builtin_bit_cast(unsigned short, (_Float16)L);
    return au | (bu << 8) | ((uint32)hb << 16);
}

// chunk of 4 px in 3 float4: {r0,g0,b0,r1},{g1,b1,r2,g2},{b2,r3,g3,b3}
__device__ __forceinline__ void chunk_pack(const float4& A, const float4& B,
                                           const float4& C, uint32* pk,
                                           float& m1, float& m2) {
    float L, a, b;
    px(A.x, A.y, A.z, L, a, b); m1 = fminf(m1, L); m2 = fminf(m2, 100.0f - L); pk[0] = packpx(L, a, b);
    px(A.w, B.x, B.y, L, a, b); m1 = fminf(m1, L); m2 = fminf(m2, 100.0f - L); pk[1] = packpx(L, a, b);
    px(B.z, B.w, C.x, L, a, b); m1 = fminf(m1, L); m2 = fminf(m2, 100.0f - L); pk[2] = packpx(L, a, b);
    px(C.y, C.z, C.w, L, a, b); m1 = fminf(m1, L); m2 = fminf(m2, 100.0f - L); pk[3] = packpx(L, a, b);
}

// Cooperative single-pass: 2048 blocks x 256 threads = exact co-residency at
// <=64 VGPR (8 blocks/CU, 32 waves/CU). 4 blocks per image, 16 px/thread kept
// in 16 VGPRs as u8 a | u8 b<<8 | f16 L<<16 (verified encoding). Software-
// pipelined loads, block partial-min -> ws, grid.sync, rescale + store.
// Breaks the R1/R3 lockstep (2 monolithic 16-wave blocks/CU, sum-of-phases).
__global__ __launch_bounds__(256, 8) void k_coop(const float* __restrict__ x,
                                                 float* __restrict__ out,
                                                 float* __restrict__ hdr) {
    const int bid = blockIdx.x, t = threadIdx.x;
    const int img = bid >> 2, sub = bid & 3;
    const size_t base4 = (size_t)img * 12288 + (size_t)sub * 3072;
    const float4* __restrict__ in4 = (const float4*)x + base4;

    uint32 pk[16];
    float m1 = 3.4e38f, m2 = 3.4e38f;            // min(L), min(100-L)

    // software pipeline: chunk c+1 loads in flight during chunk c compute
    float4 A = in4[3 * t], B = in4[3 * t + 1], C = in4[3 * t + 2];
#pragma unroll
    for (int c = 0; c < 4; ++c) {
        float4 An, Bn, Cn;
        if (c < 3) {
            const int o = (c + 1) * 768 + 3 * t;
            An = in4[o]; Bn = in4[o + 1]; Cn = in4[o + 2];
        }
        chunk_pack(A, B, C, &pk[4 * c], m1, m2);
        A = An; B = Bn; C = Cn;
    }

    // wave reduce (64 lanes) then 4-wave LDS reduce; one partial per block
#pragma unroll
    for (int m = 32; m; m >>= 1) {
        m1 = fminf(m1, __shfl_xor(m1, m, 64));
        m2 = fminf(m2, __shfl_xor(m2, m, 64));
    }
    __shared__ float sm[8];
    if ((t & 63) == 0) { sm[(t >> 6) * 2] = m1; sm[(t >> 6) * 2 + 1] = m2; }
    __syncthreads();
    if (t == 0) {
        hdr[bid * 2]     = fminf(fminf(sm[0], sm[2]), fminf(sm[4], sm[6]));
        hdr[bid * 2 + 1] = fminf(fminf(sm[1], sm[3]), fminf(sm[5], sm[7]));
    }

    cg::this_grid().sync();

    // per-image final min: 8 floats = 2 float4, broadcast L2 reads
    const float4 h0 = ((const float4*)hdr)[img * 2];
    const float4 h1 = ((const float4*)hdr)[img * 2 + 1];
    const float Lmin = fminf(fminf(h0.x, h0.z), fminf(h1.x, h1.z));
    const float M2   = fminf(fminf(h0.y, h0.w), fminf(h1.y, h1.w));
    const float s = 1.0f / ((100.0f - M2) - Lmin);

    float4* __restrict__ o4 = (float4*)out + base4;
#pragma unroll
    for (int c = 0; c < 4; ++c) {
        float L[4], a[4], b[4];
#pragma unroll
        for (int i = 0; i < 4; ++i) {
            const uint32 v = pk[4 * c + i];
            a[i] = (float)(v & 255u) * (1.0f / 255.0f);
            b[i] = (float)((v >> 8) & 255u) * (1.0f / 255.0f);
            L[i] = ((float)__builtin_bit_cast(_Float16, (unsigned short)(v >> 16)) - Lmin) * s;
        }
        const int o = c * 768 + 3 * t;
        o4[o]     = make_float4(L[0], a[0], b[0], L[1]);
        o4[o + 1] = make_float4(a[1], b[1], L[2], a[2]);
        o4[o + 2] = make_float4(b[2], L[3], a[3], b[3]);
    }
}

// ---- fallback: round-1 fused kernel (68 us, verified) if coop launch fails ----
__global__ __launch_bounds__(1024) void k_fb(const float* __restrict__ x,
                                             float* __restrict__ out) {
    const int img = blockIdx.x, t = threadIdx.x;
    const size_t base = (size_t)img * 49152;
    const float* __restrict__ in = x + base;
    float* __restrict__ o = out + base;

    uint32 pk[16];
    float m1 = 3.4e38f, m2 = 3.4e38f;
#pragma unroll
    for (int i = 0; i < 16; ++i) {
        const int p = t + (i << 10);
        const float* q = in + 3 * p;
        float L, a01, b01;
        px(q[0], q[1], q[2], L, a01, b01);
        m1 = fminf(m1, L);
        m2 = fminf(m2, 100.0f - L);
        pk[i] = packpx(L, a01, b01);
    }
#pragma unroll
    for (int m = 32; m; m >>= 1) {
        m1 = fminf(m1, __shfl_xor(m1, m, 64));
        m2 = fminf(m2, __shfl_xor(m2, m, 64));
    }
    __shared__ float sm[32];
    if ((t & 63) == 0) { sm[(t >> 6) * 2] = m1; sm[(t >> 6) * 2 + 1] = m2; }
    __syncthreads();
    float Lmin = 3.4e38f, M2 = 3.4e38f;
#pragma unroll
    for (int i = 0; i < 16; ++i) {
        Lmin = fminf(Lmin, sm[2 * i]);
        M2   = fminf(M2,   sm[2 * i + 1]);
    }
    const float s = 1.0f / ((100.0f - M2) - Lmin);
#pragma unroll
    for (int i = 0; i < 16; ++i) {
        const int p = t + (i << 10);
        const uint32 v = pk[i];
        float* q = o + 3 * p;
        q[0] = ((float)__builtin_bit_cast(_Float16, (unsigned short)(v >> 16)) - Lmin) * s;
        q[1] = (float)(v & 255u) * (1.0f / 255.0f);
        q[2] = (float)((v >> 8) & 255u) * (1.0f / 255.0f);
    }
}

extern "C" void kernel_launch(void* const* d_in, const int* in_sizes, int n_in,
                              void* d_out, int out_size, void* d_ws, size_t ws_size,
                              hipStream_t stream) {
    (void)in_sizes; (void)n_in; (void)out_size;
    const float* x = (const float*)d_in[0];
    float* out = (float*)d_out;
    float* hdr = (float*)d_ws;

    bool done = false;
    if (ws_size >= 2048ull * 2ull * sizeof(float)) {
        void* args[] = {(void*)&x, (void*)&out, (void*)&hdr};
        hipError_t e = hipLaunchCooperativeKernel((const void*)k_coop, dim3(2048),
                                                  dim3(256), args, 0, stream);
        done = (e == hipSuccess);
    }
    if (!done) {
        k_fb<<<512, 1024, 0, stream>>>(x, out);
    }
}